// Round 10
// baseline (469.819 us; speedup 1.0000x reference)
//
#include <hip/hip_runtime.h>
#include <cstdint>
#include <cstddef>

// Problem constants (fixed by reference)
#define NR   268
#define NB   256
#define NN   (NR*NB)        // 68608 nodes
#define IC   256
#define OC   64
#define DEG  32
#define EPG  (NR*DEG)       // 8576 edges per graph
#define NE   (NN*DEG)       // 2195456 edges
#define KK   214            // top-k per graph

// d_out layout (floats, concatenated outputs)
#define XP_OFF 0            // x_pooled  (256*214, 64)
#define BP_OFF 3506176      // batch_pooled (256*214)
#define SC_OFF 3560960      // scores (68608)
#define PM_OFF 3629568      // perm (256*214)

// workspace layout (float offsets)
#define WS_ROIK 0           // 268*256*64
#define WS_XT   4390912     // xt2: [r][g][o] = 268*256*64
#define WS_HB   8781824     // 68608*64  (post-LN h, node-major [g][r][o])

// ---------------------------------------------------------------------------
// K0: cw = softmax(roi_community); roi_k[r] = sum_c cw[c] * basis[c]
// ---------------------------------------------------------------------------
__global__ __launch_bounds__(256) void k_roik(const float* __restrict__ rc,
                                              const float* __restrict__ basis,
                                              float* __restrict__ roik) {
    int r = blockIdx.x;
    float c[7];
    float m = -1e30f;
#pragma unroll
    for (int j = 0; j < 7; ++j) { c[j] = rc[r*7 + j]; m = fmaxf(m, c[j]); }
    float s = 0.f;
#pragma unroll
    for (int j = 0; j < 7; ++j) { c[j] = expf(c[j] - m); s += c[j]; }
    float inv = 1.f / s;
#pragma unroll
    for (int j = 0; j < 7; ++j) c[j] *= inv;
    for (int idx = threadIdx.x; idx < IC*OC; idx += 256) {
        float acc = 0.f;
#pragma unroll
        for (int j = 0; j < 7; ++j) acc = fmaf(c[j], basis[j*IC*OC + idx], acc);
        roik[(size_t)r*IC*OC + idx] = acc;
    }
}

// ---------------------------------------------------------------------------
// K1: xt2[r][g][o] = x[g*NR+r] @ roi_k[r].
// R9's lane=graph mapping strided adjacent lanes by 68-274 KB: 4x HBM read
// amplification on x + scattered stores. New mapping: lane=channel o,
// wave=16 graphs. W tile -> 32 coalesced 256B wave-loads into regs; x rows
// are WAVE-UNIFORM -> s_loads (64B scalar chunks, no amplification);
// stores coalesced 256B per graph. No LDS.
// ---------------------------------------------------------------------------
__global__ __launch_bounds__(512) void k_xtf(const float* __restrict__ x,
                                             const float* __restrict__ roik,
                                             float* __restrict__ xt2) {
    int bid = blockIdx.x;
    int r = bid >> 1;                  // ROI
    int half = bid & 1;
    int tid = threadIdx.x;
    int o = tid & 63;
    int wu = tid >> 6;                 // 0..7
    int gbase = half*128 + wu*16;      // this wave's 16 graphs

    const float* __restrict__ wk = roik + (size_t)r * (IC*OC);

    float acc[16];
#pragma unroll
    for (int i = 0; i < 16; ++i) acc[i] = 0.f;

    for (int kt = 0; kt < IC; kt += 32) {
        float wreg[32];
#pragma unroll
        for (int j = 0; j < 32; ++j)
            wreg[j] = wk[(size_t)(kt + j) * OC + o];     // coalesced 256B/load
#pragma unroll 4
        for (int gi = 0; gi < 16; ++gi) {
            const float* __restrict__ xr =
                x + ((size_t)(gbase + gi) * NR + r) * IC + kt;  // uniform -> s_load
            float a = acc[gi];
#pragma unroll
            for (int j = 0; j < 32; ++j) a = fmaf(xr[j], wreg[j], a);
            acc[gi] = a;
        }
    }

#pragma unroll
    for (int gi = 0; gi < 16; ++gi)
        xt2[((size_t)r * 256 + (gbase + gi)) * OC + o] = acc[gi];  // coalesced
}

// ---------------------------------------------------------------------------
// K2 (fused): per graph — CSR build IN LDS (16-replica count, scan, place
// into LDS meta; kills k_csr + its 35 MB meta round-trip and the ~200-900 cyc
// uniform global meta loads: LDS uniform ds_read_b64 instead) -> stage xts
// (overlaying the dead cnt/cur region) -> gather + Taylor gate + bias + ELU +
// LayerNorm -> inline scores (rowbuf bounce, W1 in 16 named float4 regs) ->
// bitonic top-214 -> pooled outputs.
// Dynamic LDS = meta 68608 + xts 68608 = 137216 B (<=160 KB HW; >64 KB works:
// R8/R9 ran 68.6 KB). 256 blocks x 1024 thr = 1 block/CU, 16 waves.
// ---------------------------------------------------------------------------
__global__ __launch_bounds__(1024, 4) void k_fused(
    const float* __restrict__ xt2,
    const int* __restrict__ ei,
    const float* __restrict__ ea,
    float* __restrict__ hbw,
    const float* __restrict__ ew_w, const float* __restrict__ ew_b,
    const float* __restrict__ conv_bias,
    const float* __restrict__ ln_g, const float* __restrict__ ln_b,
    const float* __restrict__ w1, const float* __restrict__ b1,
    const float* __restrict__ w2, const float* __restrict__ b2,
    float* __restrict__ out)
{
    extern __shared__ float dynl[];          // [meta 17152 floats][xts 17152]
    float2* metaL = (float2*)dynl;           // 8576 x 8B
    float*  xts   = dynl + 17152;            // 268*64 floats
    unsigned* cnt = (unsigned*)(dynl + 17152);   // overlay on xts (dead later)
    unsigned* cur = cnt + 16*NR;

    __shared__ float rowbuf[16][OC];         // per-wave h row bounce
    __shared__ float scl[NR];
    __shared__ unsigned long long keys[512];
    __shared__ unsigned rows_s[NR + 1];
    __shared__ unsigned sscan[NR];

    int g = blockIdx.x;
    int tid = threadIdx.x;
    int o = tid & 63, w = tid >> 6;          // 16 waves

    int ebase = g * EPG;

    // ---- CSR build: count ----
    for (int i = tid; i < 16*NR; i += 1024) cnt[i] = 0u;
    __syncthreads();
    for (int e = tid; e < EPG; e += 1024) {
        int ld = ei[NE + ebase + e] - g * NR;
        atomicAdd(&cnt[w*NR + ld], 1u);
    }
    __syncthreads();
    for (int r = tid; r < NR; r += 1024) {
        unsigned t = 0;
#pragma unroll
        for (int s = 0; s < 16; ++s) t += cnt[s*NR + r];
        sscan[r] = t;
    }
    __syncthreads();
    if (tid < 64) {                          // wave 0: exclusive scan of 268
        unsigned run = 0;
        for (int base = 0; base < NR; base += 64) {
            int idx = base + tid;
            unsigned v = (idx < NR) ? sscan[idx] : 0u;
            unsigned orig = v;
#pragma unroll
            for (int s = 1; s < 64; s <<= 1) {
                int t = __shfl_up((int)v, (unsigned)s, 64);
                if (tid >= s) v += (unsigned)t;
            }
            if (idx < NR) rows_s[idx] = run + v - orig;
            run += (unsigned)__shfl((int)v, 63, 64);
        }
        if (tid == 0) rows_s[NR] = (unsigned)EPG;
    }
    __syncthreads();
    for (int r = tid; r < NR; r += 1024) {
        unsigned base = rows_s[r];
#pragma unroll
        for (int s = 0; s < 16; ++s) { cur[s*NR + r] = base; base += cnt[s*NR + r]; }
    }
    __syncthreads();
    // ---- place into LDS meta ----
    for (int e = tid; e < EPG; e += 1024) {
        int src = ei[ebase + e];
        int dst = ei[NE + ebase + e];
        float a = ea[ebase + e];
        int ld = dst - g * NR;
        unsigned pos = atomicAdd(&cur[w*NR + ld], 1u);
        float2 mv; mv.x = __int_as_float((src - g*NR) * OC); mv.y = a;
        metaL[pos] = mv;
    }
    __syncthreads();

    // ---- stage xts (overwrites cnt/cur region). xt2 is ROI-major: coalesced.
    {
        float4* d4 = (float4*)xts;
        for (int i = tid; i < NR*OC/4; i += 1024) {
            int r = i >> 4, c4 = i & 15;
            d4[i] = ((const float4*)(xt2 + ((size_t)r*256 + g) * OC))[c4];
        }
    }

    float wo = ew_w[o], bo = ew_b[o], cb = conv_bias[o];
    float lng = ln_g[o], lnb = ln_b[o];
    float w2o = w2[o], b1o = b1[o], b2s = b2[0];
    float sgself = 1.f / (1.f + expf(-(wo + bo)));

    // degree-4 Taylor of sigmoid(wo*a + bo) in da = a - 0.5
    float z0 = fmaf(0.5f, wo, bo);
    float s  = 1.f / (1.f + expf(-z0));
    float u  = s * (1.f - s);
    float d2 = u * (1.f - 2.f*s);
    float d3 = u * (1.f - 6.f*u);
    float d4c = d2 * (1.f - 12.f*u);
    float k1 = u * wo;
    float k2 = d2 * wo*wo * 0.5f;
    float k3 = d3 * wo*wo*wo * (1.f/6.f);
    float k4 = d4c * wo*wo*wo*wo * (1.f/24.f);
    #define GATE(a_) fmaf(fmaf(fmaf(fmaf(k4,(a_),k3),(a_),k2),(a_),k1),(a_),s)

    // W1 column o in 16 named float4 regs (64-float arrays demote to scratch)
    #define LOADW(j) float4 wc##j = make_float4(w1[(4*j+0)*OC+o], w1[(4*j+1)*OC+o], \
                                                w1[(4*j+2)*OC+o], w1[(4*j+3)*OC+o]);
    LOADW(0)  LOADW(1)  LOADW(2)  LOADW(3)
    LOADW(4)  LOADW(5)  LOADW(6)  LOADW(7)
    LOADW(8)  LOADW(9)  LOADW(10) LOADW(11)
    LOADW(12) LOADW(13) LOADW(14) LOADW(15)
    #undef LOADW

    __syncthreads();

    // ---- gather + ELU + LN + score ----
    for (int r = w; r < NR; r += 16) {
        unsigned js = rows_s[r], je = rows_s[r + 1];
        float acc = xts[r*OC + o] * sgself;     // self loop (attr = 1)
        unsigned j = js;
        for (; j + 8 <= je; j += 8) {
            float2 m0 = metaL[j],   m1 = metaL[j+1], m2 = metaL[j+2], m3 = metaL[j+3];
            float2 m4 = metaL[j+4], m5 = metaL[j+5], m6 = metaL[j+6], m7 = metaL[j+7];
            float x0 = xts[__float_as_int(m0.x) + o];
            float x1 = xts[__float_as_int(m1.x) + o];
            float x2 = xts[__float_as_int(m2.x) + o];
            float x3 = xts[__float_as_int(m3.x) + o];
            float x4 = xts[__float_as_int(m4.x) + o];
            float x5 = xts[__float_as_int(m5.x) + o];
            float x6 = xts[__float_as_int(m6.x) + o];
            float x7 = xts[__float_as_int(m7.x) + o];
            acc = fmaf(x0, GATE(m0.y - 0.5f), acc);
            acc = fmaf(x1, GATE(m1.y - 0.5f), acc);
            acc = fmaf(x2, GATE(m2.y - 0.5f), acc);
            acc = fmaf(x3, GATE(m3.y - 0.5f), acc);
            acc = fmaf(x4, GATE(m4.y - 0.5f), acc);
            acc = fmaf(x5, GATE(m5.y - 0.5f), acc);
            acc = fmaf(x6, GATE(m6.y - 0.5f), acc);
            acc = fmaf(x7, GATE(m7.y - 0.5f), acc);
        }
        for (; j < je; ++j) {
            float2 m = metaL[j];
            float xv = xts[__float_as_int(m.x) + o];
            acc = fmaf(xv, GATE(m.y - 0.5f), acc);
        }
        acc += cb;
        float v = acc > 0.f ? acc : expm1f(acc);   // ELU (alpha=1)
        // LayerNorm across the wave's 64 lanes
        float s1 = v;
#pragma unroll
        for (int m = 1; m < 64; m <<= 1) s1 += __shfl_xor(s1, m, 64);
        float mu = s1 * (1.f/64.f);
        float d = v - mu;
        float s2 = d * d;
#pragma unroll
        for (int m = 1; m < 64; m <<= 1) s2 += __shfl_xor(s2, m, 64);
        float rsd = rsqrtf(s2 * (1.f/64.f) + 1e-5f);
        float h = fmaf(d * rsd, lng, lnb);
        hbw[((size_t)g * NR + r)*OC + o] = h;      // for pool phase (L2-hot)
        rowbuf[w][o] = h;
        {
            const float* hr = rowbuf[w];
            float t0 = b1o, t1 = 0.f, t2 = 0.f, t3 = 0.f;
            #define STEP(j) { float4 h4 = *(const float4*)(hr + 4*j); \
                t0 = fmaf(h4.x, wc##j.x, t0); t1 = fmaf(h4.y, wc##j.y, t1); \
                t2 = fmaf(h4.z, wc##j.z, t2); t3 = fmaf(h4.w, wc##j.w, t3); }
            STEP(0)  STEP(1)  STEP(2)  STEP(3)
            STEP(4)  STEP(5)  STEP(6)  STEP(7)
            STEP(8)  STEP(9)  STEP(10) STEP(11)
            STEP(12) STEP(13) STEP(14) STEP(15)
            #undef STEP
            float t = (t0 + t1) + (t2 + t3);
            float a2 = fminf(fmaxf(2.f * t, -80.f), 80.f);
            float y = expf(a2);
            float th = (y - 1.f) / (y + 1.f);
            float p = th * w2o;
#pragma unroll
            for (int m = 1; m < 64; m <<= 1) p += __shfl_xor(p, m, 64);
            if (o == 0) {
                float sc = p + b2s;
                scl[r] = sc;
                out[SC_OFF + (size_t)g * NR + r] = sc;
            }
        }
    }
    #undef GATE
    __syncthreads();

    // ---- bitonic top-K over 512 slots ----
    for (int i = tid; i < 512; i += 1024) {
        unsigned long long key = 0ull;
        if (i < NR) {
            unsigned ub = __float_as_uint(scl[i]);
            unsigned ou = (ub & 0x80000000u) ? ~ub : (ub | 0x80000000u);
            key = (((unsigned long long)ou) << 32) |
                  (unsigned long long)(0xFFFFFFFFu - (unsigned)i);
        }
        keys[i] = key;
    }
    for (int kk = 2; kk <= 512; kk <<= 1) {
        for (int j = kk >> 1; j > 0; j >>= 1) {
            __syncthreads();
            if (tid < 256) {
                int i = ((tid & ~(j - 1)) << 1) | (tid & (j - 1));
                int p = i | j;
                unsigned long long a = keys[i], bb = keys[p];
                bool desc = ((i & kk) == 0);
                if (desc ? (a < bb) : (a > bb)) { keys[i] = bb; keys[p] = a; }
            }
        }
    }
    __syncthreads();

    // ---- pooled outputs (h re-read from just-written L2-hot hbw) ----
    for (int k = w; k < KK; k += 16) {
        unsigned long long kv = keys[k];
        int r = (int)(0xFFFFFFFFu - (unsigned)(kv & 0xFFFFFFFFull));
        float v = scl[r];
        float gate = 1.f / (1.f + expf(-v));
        float hvv = hbw[((size_t)g * NR + r)*OC + o];
        out[XP_OFF + ((size_t)g*KK + k)*64 + o] = hvv * gate;
        if (o == 0) {
            out[BP_OFF + (size_t)g*KK + k] = (float)g;
            out[PM_OFF + (size_t)g*KK + k] = (float)(g*NR + r);
        }
    }
}

// ---------------------------------------------------------------------------
extern "C" void kernel_launch(void* const* d_in, const int* in_sizes, int n_in,
                              void* d_out, int out_size, void* d_ws, size_t ws_size,
                              hipStream_t stream) {
    const float* x     = (const float*)d_in[0];
    const int*   ei    = (const int*)d_in[1];
    const float* ea    = (const float*)d_in[2];
    // d_in[3] batch: structurally known (g = n / NR), unused
    const float* basis = (const float*)d_in[4];
    const float* rc    = (const float*)d_in[5];
    const float* ew_w  = (const float*)d_in[6];
    const float* ew_b  = (const float*)d_in[7];
    const float* cbias = (const float*)d_in[8];
    const float* ln_g  = (const float*)d_in[9];
    const float* ln_b  = (const float*)d_in[10];
    const float* w1    = (const float*)d_in[11];
    const float* b1    = (const float*)d_in[12];
    const float* w2    = (const float*)d_in[13];
    const float* b2    = (const float*)d_in[14];
    float* out = (float*)d_out;

    float* wsf = (float*)d_ws;
    float* roik = wsf + WS_ROIK;
    float* xt2  = wsf + WS_XT;
    float* hbw  = wsf + WS_HB;

    k_roik <<<dim3(NR),   dim3(256), 0, stream>>>(rc, basis, roik);
    k_xtf  <<<dim3(NR*2), dim3(512), 0, stream>>>(x, roik, xt2);
    k_fused<<<dim3(NB),   dim3(1024), 137216, stream>>>(
                                                  xt2, ei, ea, hbw,
                                                  ew_w, ew_b, cbias, ln_g, ln_b,
                                                  w1, b1, w2, b2, out);
}